// Round 11
// baseline (436.332 us; speedup 1.0000x reference)
//
#include <hip/hip_runtime.h>
#include <cstdint>
#include <cstddef>

typedef __bf16 bf16;
typedef bf16 bf16x2 __attribute__((ext_vector_type(2)));
typedef bf16 bf16x4 __attribute__((ext_vector_type(4)));
typedef bf16 bf16x8 __attribute__((ext_vector_type(8)));
typedef float f32x4 __attribute__((ext_vector_type(4)));

// async global->LDS, 16B per lane; dest must be wave-uniform base (HW adds lane*16)
__device__ __forceinline__ void gll16(const void* g, void* l) {
  __builtin_amdgcn_global_load_lds((__attribute__((address_space(1))) void*)g,
                                   (__attribute__((address_space(3))) void*)l, 16, 0, 0);
}

// ---------------- graph preprocessing ----------------
__global__ void k_count(const int* __restrict__ ei, int* __restrict__ deg, int E) {
  int e = blockIdx.x * 256 + threadIdx.x;
  if (e < E) atomicAdd(&deg[ei[E + e]], 1);   // dst = ei[E+e]
}

// R19: single-workgroup fused scan (replaces scan1+scan2+scan3 = 3 launches).
// 1024 threads, ceil(N/1024) contiguous elems each: serial per-thread sum ->
// Hillis-Steele block scan -> serial walk writes roff/dinv. ~400KB r+w on one
// CU ~= 3-4us; saves 2 launch gaps and 2 kernel startups.
__global__ __launch_bounds__(1024) void k_scan(const int* __restrict__ deg,
                                               int* __restrict__ roff,
                                               float* __restrict__ dinv, int N) {
  __shared__ int ts[1024];
  int t = threadIdx.x;
  int per = (N + 1023) / 1024;
  int lo = t * per;
  int hi = min(lo + per, N);
  int sum = 0;
  for (int i = lo; i < hi; ++i) sum += deg[i] - 1;
  ts[t] = sum;
  __syncthreads();
  for (int off = 1; off < 1024; off <<= 1) {
    int add = (t >= off) ? ts[t - off] : 0;
    __syncthreads();
    ts[t] += add;
    __syncthreads();
  }
  int base = (t > 0) ? ts[t - 1] : 0;   // exclusive prefix of this range
  for (int i = lo; i < hi; ++i) {
    int d = deg[i];
    roff[i] = base;
    base += d - 1;
    dinv[i] = rsqrtf((float)d);
  }
  if (hi == N) roff[N] = base;          // last real thread (and empty tails, same value)
}

// csr entry = {src, dinv[src]}: the per-edge weight rides the coalesced index
// load in agg (R16; removed the scattered per-edge dinv gather).
__global__ void k_scatter(const int* __restrict__ ei, const int* __restrict__ roff,
                          int* __restrict__ cur, int2* __restrict__ csr,
                          const float* __restrict__ dinv, int E) {
  int e = blockIdx.x * 256 + threadIdx.x;
  if (e >= E) return;
  int d = ei[E + e];
  int sidx = ei[e];
  int p = atomicAdd(&cur[d], 1);
  int2 val;
  val.x = sidx;
  val.y = __float_as_int(dinv[sidx]);
  csr[roff[d] + p] = val;   // src + weight
}

// ---------------- dtype conversion + deg/cur init (one launch) ----------------
__global__ void k_cvt(const float* __restrict__ x, bf16* __restrict__ xb,
                      size_t totalx, int nx,
                      const float* __restrict__ W1, const float* __restrict__ W2,
                      const float* __restrict__ Wl, bf16* __restrict__ w1t,
                      bf16* __restrict__ w2t, bf16* __restrict__ wlt,
                      int* __restrict__ deg, int* __restrict__ cur, int N) {
  if ((int)blockIdx.x < nx) {
    int ii = blockIdx.x * 256 + threadIdx.x;
    if (ii < N) { deg[ii] = 1; cur[ii] = 0; }   // self-loop degree init, fused
    size_t base = ((size_t)blockIdx.x * 256 + threadIdx.x) * 4;
    if (base >= totalx) return;
    const float4 v = *(const float4*)(x + base);
    bf16x4 o;
    o[0] = (bf16)v.x; o[1] = (bf16)v.y; o[2] = (bf16)v.z; o[3] = (bf16)v.w;
    *(bf16x4*)(xb + base) = o;
  } else {
    int i = (blockIdx.x - nx) * 256 + threadIdx.x;   // covers 229376 exactly
    if (i < 32768) {
      int n = i >> 7, k = i & 127;
      w1t[i] = (bf16)W1[(size_t)k * 256 + n];
    } else if (i < 163840) {
      int j = i - 32768;
      int n = j >> 8, k = j & 255;
      w2t[j] = (bf16)W2[(size_t)k * 512 + n];
    } else {
      int j = i - 163840;
      int n = j >> 9, k = j & 511;
      wlt[j] = (bf16)Wl[(size_t)k * 128 + n];
    }
  }
}

// ---------------- bf16 MFMA GEMM: C[M,NOUT] = A[M,K] @ Bt[NOUT,K]^T ----------------
// Frozen (R12/R15/R17): line-coalesced DMA staging, 2-buffer m97 schedule,
// LDS-transpose epilogue, BN partials; XCD-grouped grid for non-FINAL
// (all NS n-stripes of an m-tile land on the same XCD -> A-panel L2 reuse);
// FINAL fuses BN2+ReLU into reg-staged A.
template<int K, int NOUT, bool FINAL>
__global__ __launch_bounds__(256, 4) void k_gemm(const bf16* __restrict__ A,
                                                 const bf16* __restrict__ Bt,
                                                 bf16* __restrict__ outB,
                                                 float* __restrict__ outF,
                                                 const float* __restrict__ bias,
                                                 float* __restrict__ part,
                                                 const float* __restrict__ scA,
                                                 const float* __restrict__ shA,
                                                 int Mreal) {
  constexpr int MT    = FINAL ? 64 : 128;   // m-tile rows
  constexpr int RPW   = MT / 32;            // 16-row subtiles per wave
  constexpr int NSTEP = K / 32;
  constexpr int SB    = MT * 4 + 512;       // uint4 slots per buffer (A + B)
  constexpr int NAI   = (MT * 4) / 256;     // A DMA issues per thread (2 or 1)
  constexpr int NS    = NOUT / 128;         // n-stripes (1, 2 or 4)
  constexpr int NSH   = (NS == 4) ? 2 : ((NS == 2) ? 1 : 0);

  const int GXr = (Mreal + 127) >> 7;       // real m-tiles (391)
  int mtile, m0, n0;
  if constexpr (!FINAL) {
    mtile = blockIdx.x + ((blockIdx.y >> NSH) << 3);
    if (mtile >= GXr) return;               // uniform exit, before any barrier
    m0 = mtile * 128;
    n0 = (blockIdx.y & (NS - 1)) * 128;
  } else {
    mtile = blockIdx.y;
    m0 = blockIdx.y * MT;
    n0 = 0;
  }

  __shared__ uint4 lds[2 * SB];
  __shared__ float sstm[512];               // stats scratch, DISJOINT from lds
  __shared__ float scsh[FINAL ? 1024 : 4];  // FINAL: scale[512] + shift[512]

  const int tid = threadIdx.x;
  const int wv = tid >> 6;
  const int lane = tid & 63;
  const int q = lane >> 4, mr = lane & 15;
  const int rw = (wv >> 1) * (MT / 2), cw = (wv & 1) * 64;
  const int wslot = wv << 6;
  const int qx = q ^ (mr & 3);   // read-side in-row XOR (row&3 == mr&3)

  // coalesced per-lane global sources: dest granule slot=p*256+tid (linear)
  // holds (row = slot>>2, chunk = (slot&3)^(row&3)) of the current K-step.
  const bf16* srcA[NAI];
#pragma unroll
  for (int p = 0; p < NAI; ++p) {
    int slot = p * 256 + tid;
    int row = slot >> 2;
    int c = (slot & 3) ^ (row & 3);
    srcA[p] = A + (size_t)(m0 + row) * K + c * 8;
  }
  const bf16* srcB[2];
#pragma unroll
  for (int p = 0; p < 2; ++p) {
    int slot = p * 256 + tid;
    int row = slot >> 2;
    int c = (slot & 3) ^ (row & 3);
    srcB[p] = Bt + (size_t)(n0 + row) * K + c * 8;
  }
  const int cA8 = (((tid & 3) ^ ((tid >> 2) & 3))) * 8;   // FINAL A chunk base

  auto issue = [&](int t) {
    uint4* bb = lds + (t & 1) * SB;
    if constexpr (!FINAL) {
#pragma unroll
      for (int p = 0; p < NAI; ++p)
        gll16(srcA[p] + t * 32, bb + p * 256 + wslot);
    }
#pragma unroll
    for (int p = 0; p < 2; ++p)
      gll16(srcB[p] + t * 32, bb + MT * 4 + p * 256 + wslot);
  };

  // FINAL: transform raw A (BN2+ReLU) and write to the linear LDS slot
  auto xformA = [&](bf16x8 ra, int t) {
    int kb = t * 32 + cA8;
    float4 s0 = *(const float4*)&scsh[kb];
    float4 s1 = *(const float4*)&scsh[kb + 4];
    float4 h0 = *(const float4*)&scsh[512 + kb];
    float4 h1 = *(const float4*)&scsh[512 + kb + 4];
    bf16x8 o;
    o[0] = (bf16)fmaxf(0.f, (float)ra[0] * s0.x + h0.x);
    o[1] = (bf16)fmaxf(0.f, (float)ra[1] * s0.y + h0.y);
    o[2] = (bf16)fmaxf(0.f, (float)ra[2] * s0.z + h0.z);
    o[3] = (bf16)fmaxf(0.f, (float)ra[3] * s0.w + h0.w);
    o[4] = (bf16)fmaxf(0.f, (float)ra[4] * s1.x + h1.x);
    o[5] = (bf16)fmaxf(0.f, (float)ra[5] * s1.y + h1.y);
    o[6] = (bf16)fmaxf(0.f, (float)ra[6] * s1.z + h1.z);
    o[7] = (bf16)fmaxf(0.f, (float)ra[7] * s1.w + h1.w);
    lds[(t & 1) * SB + tid] = *(uint4*)&o;
  };

  f32x4 acc[RPW][4];
#pragma unroll
  for (int r = 0; r < RPW; ++r)
#pragma unroll
    for (int c = 0; c < 4; ++c) acc[r][c] = (f32x4){0.f, 0.f, 0.f, 0.f};

  if constexpr (FINAL) {
    for (int i = tid; i < 1024; i += 256) scsh[i] = (i < 512) ? scA[i] : shA[i - 512];
    issue(0);                              // B DMA only
    bf16x8 ra0 = *(const bf16x8*)srcA[0];
    __syncthreads();                       // scsh visible (B also drained)
    xformA(ra0, 0);
    __syncthreads();                       // buf0 A published
  } else {
    issue(0);
    __syncthreads();                       // drains DMA: buf 0 ready
  }

#pragma unroll
  for (int t = 0; t < NSTEP; ++t) {
    bf16x8 raN;
    if (t + 1 < NSTEP) {
      issue(t + 1);                        // in flight across the compute phase
      if constexpr (FINAL) raN = *(const bf16x8*)(srcA[0] + (t + 1) * 32);
    }

    const uint4* bb = lds + (t & 1) * SB;
    const bf16x8* bA = (const bf16x8*)bb;
    const bf16x8* bB = (const bf16x8*)(bb + MT * 4);
    bf16x8 bfr[4];
#pragma unroll
    for (int c = 0; c < 4; ++c) {
      int rb = cw + c * 16 + mr;
      bfr[c] = bB[rb * 4 + qx];
    }
#pragma unroll
    for (int r = 0; r < RPW; ++r) {
      int ra = rw + r * 16 + mr;
      bf16x8 af = bA[ra * 4 + qx];
#pragma unroll
      for (int c = 0; c < 4; ++c)
        acc[r][c] = __builtin_amdgcn_mfma_f32_16x16x32_bf16(af, bfr[c], acc[r][c], 0, 0, 0);
    }
    if constexpr (FINAL) {
      if (t + 1 < NSTEP) xformA(raN, t + 1);   // write buf t+1 A (pre-barrier)
    }
    __syncthreads();   // drains next tile's DMA (after compute) + read fence
  }

  // C/D layout: col = lane&15, row = (lane>>4)*4 + reg (m89/m91-verified)
  if constexpr (!FINAL) {
    bf16* ot = (bf16*)lds;                  // [128][128] bf16, XOR-swizzled cols
#pragma unroll
    for (int c = 0; c < 4; ++c) {
      float s0 = 0.f, s1 = 0.f;
#pragma unroll
      for (int r = 0; r < RPW; ++r) {
#pragma unroll
        for (int i = 0; i < 4; ++i) {
          int rl = rw + r * 16 + q * 4 + i;
          int cl = cw + c * 16 + mr;
          float v = acc[r][c][i];
          ot[rl * 128 + (cl ^ (((rl >> 2) & 3) << 4))] = (bf16)v;
          if (m0 + rl < Mreal) { s0 += v; s1 += v * v; }
        }
      }
      s0 += __shfl_xor(s0, 16, 64); s0 += __shfl_xor(s0, 32, 64);
      s1 += __shfl_xor(s1, 16, 64); s1 += __shfl_xor(s1, 32, 64);
      if (q == 0) {
        sstm[wv * 64 + c * 16 + mr] = s0;
        sstm[256 + wv * 64 + c * 16 + mr] = s1;
      }
    }
    __syncthreads();
    {
      // combine wave pairs, plain-store per-block partials (no atomics)
      int ssel = tid >> 7, cl = tid & 127;
      int hi = cl >> 6, lo = cl & 63;
      float v = sstm[ssel * 256 + hi * 64 + lo] + sstm[ssel * 256 + (hi + 2) * 64 + lo];
      part[((size_t)ssel * GXr + mtile) * NOUT + n0 + cl] = v;
    }
    // full-line coalesced stores: 16 lanes cover one 256B row
#pragma unroll
    for (int p = 0; p < 8; ++p) {
      int rl = p * 16 + (tid >> 4), c8 = tid & 15;
      uint4 v = *(const uint4*)(ot + rl * 128 + ((c8 * 8) ^ (((rl >> 2) & 3) << 4)));
      *(uint4*)(outB + (size_t)(m0 + rl) * NOUT + n0 + c8 * 8) = v;
    }
  } else {
    // FINAL LDS is 2*SB*16 = 24576 B; stage the [64][128] f32 tile in two halves.
    float* otf = (float*)lds;
#pragma unroll
    for (int h = 0; h < 2; ++h) {
      __syncthreads();
#pragma unroll
      for (int c = 0; c < 4; ++c)
#pragma unroll
        for (int r = 0; r < RPW; ++r)
#pragma unroll
          for (int i = 0; i < 4; ++i) {
            int rl = rw + r * 16 + q * 4 + i;
            if ((rl >> 5) != h) continue;   // rows [h*32, h*32+32)
            int cl = cw + c * 16 + mr;
            otf[(rl - h * 32) * 128 + (cl ^ (((rl >> 2) & 3) << 4))] = acc[r][c][i];
          }
      __syncthreads();
#pragma unroll
      for (int p = 0; p < 4; ++p) {
        int rl = p * 8 + (tid >> 5), c4 = tid & 31;
        int rg = m0 + h * 32 + rl;
        if (rg < Mreal) {
          float4 v = *(const float4*)(otf + rl * 128 + ((c4 * 4) ^ ((((rl + h * 32) >> 2) & 3) << 4)));
          const float4 bv = *(const float4*)(bias + c4 * 4);
          v.x += bv.x; v.y += bv.y; v.z += bv.z; v.w += bv.w;
          *(float4*)(outF + (size_t)rg * 128 + c4 * 4) = v;
        }
      }
    }
  }
}

// ---------------- CSR aggregation (one wave per node) ----------------
// R19 = exact R17 revert (best measured: 40.7us). R18's channel-split was
// null-to-negative: FETCH 127->121MB only (slices run concurrently, so the
// instantaneous working set doesn't shrink; reuse is scattered across 8
// incoherent L2s regardless), while doubled csr/shuffle work cost +1.6us.
// agg is at the random-gather fabric floor (~120MB at ~3TB/s scattered).
template<int C, bool BN>
__global__ __launch_bounds__(64) void k_agg(const bf16* __restrict__ h,
                                            bf16* __restrict__ g,
                                            const int2* __restrict__ csr,
                                            const int* __restrict__ roff,
                                            const float* __restrict__ dinv,
                                            const float* __restrict__ scale,
                                            const float* __restrict__ shift,
                                            int N) {
  constexpr int VPL = C / 64;   // channels per lane: 2 or 4
  const int lane = threadIdx.x;
  const int v = blockIdx.x;
  if (v >= N) return;
  float sc[VPL], sh[VPL];
  if constexpr (BN) {
#pragma unroll
    for (int u = 0; u < VPL; ++u) { sc[u] = scale[lane * VPL + u]; sh[u] = shift[lane * VPL + u]; }
  }
  const float dv = dinv[v];
  float acc[VPL];
#pragma unroll
  for (int u = 0; u < VPL; ++u) acc[u] = 0.f;

  auto loadrow = [&](int src, float* o) {
    const bf16* hr = h + (size_t)src * C + lane * VPL;
    if constexpr (VPL == 2) {
      bf16x2 t = *(const bf16x2*)hr;
      o[0] = (float)t[0]; o[1] = (float)t[1];
    } else {
      bf16x4 t = *(const bf16x4*)hr;
#pragma unroll
      for (int u = 0; u < 4; ++u) o[u] = (float)t[u];
    }
  };
  auto addrow = [&](const float* vv, float ww) {
#pragma unroll
    for (int u = 0; u < VPL; ++u) {
      float xx = vv[u];
      if constexpr (BN) xx = fmaxf(0.f, xx * sc[u] + sh[u]);
      acc[u] += ww * xx;
    }
  };

  {   // self loop (becomes dv^2 after final *dv)
    float vv[VPL];
    loadrow(v, vv);
    addrow(vv, dv);
  }
  const int beg = roff[v], end = roff[v + 1];
  for (int base = beg; base < end; base += 64) {
    int cnt = min(64, end - base);
    int s = 0; float w = 0.f;
    if (lane < cnt) {
      int2 pr = csr[base + lane];
      s = pr.x; w = __int_as_float(pr.y);
    }
    int j = 0;
    for (; j + 8 <= cnt; j += 8) {
      int ss[8]; float ww[8];
#pragma unroll
      for (int k = 0; k < 8; ++k) {
        ss[k] = __shfl(s, j + k, 64);
        ww[k] = __shfl(w, j + k, 64);
      }
      float vals[8][VPL];
#pragma unroll
      for (int k = 0; k < 8; ++k) loadrow(ss[k], vals[k]);
#pragma unroll
      for (int k = 0; k < 8; ++k) addrow(vals[k], ww[k]);
    }
    for (; j + 4 <= cnt; j += 4) {
      int sa = __shfl(s, j, 64),     sb = __shfl(s, j + 1, 64);
      int sc2 = __shfl(s, j + 2, 64), sd = __shfl(s, j + 3, 64);
      float wa = __shfl(w, j, 64),     wb = __shfl(w, j + 1, 64);
      float wc = __shfl(w, j + 2, 64), wd = __shfl(w, j + 3, 64);
      float va[VPL], vb[VPL], vc[VPL], vd[VPL];
      loadrow(sa, va); loadrow(sb, vb); loadrow(sc2, vc); loadrow(sd, vd);
      addrow(va, wa); addrow(vb, wb); addrow(vc, wc); addrow(vd, wd);
    }
    for (; j < cnt; ++j) {
      int sj = __shfl(s, j, 64);
      float wj = __shfl(w, j, 64);
      float vv[VPL];
      loadrow(sj, vv);
      addrow(vv, wj);
    }
  }

  bf16* gv = g + (size_t)v * C + lane * VPL;
  if constexpr (VPL == 2) {
    bf16x2 o;
    o[0] = (bf16)(acc[0] * dv); o[1] = (bf16)(acc[1] * dv);
    *(bf16x2*)gv = o;
  } else {
    bf16x4 o;
#pragma unroll
    for (int u = 0; u < 4; ++u) o[u] = (bf16)(acc[u] * dv);
    *(bf16x4*)gv = o;
  }
}

// ---------------- BatchNorm: reduce per-block partials + finalize ----------------
// part layout: [2][GX][C]; loads coalesced (64 lanes = 64 consecutive cols)
__global__ __launch_bounds__(256) void k_bnfinal(const float* __restrict__ part,
                                                 const float* __restrict__ gamma,
                                                 const float* __restrict__ beta,
                                                 float* __restrict__ scale,
                                                 float* __restrict__ shift,
                                                 int C, int GX, float invN) {
  __shared__ float red[2][4][64];
  int t = threadIdx.x;
  int cl = t & 63, seg = t >> 6;
  int c = blockIdx.x * 64 + cl;
  float s0 = 0.f, s1 = 0.f;
  for (int b = seg; b < GX; b += 4) {
    s0 += part[(size_t)b * C + c];
    s1 += part[(size_t)(GX + b) * C + c];
  }
  red[0][seg][cl] = s0; red[1][seg][cl] = s1;
  __syncthreads();
  if (seg == 0) {
    s0 = red[0][0][cl] + red[0][1][cl] + red[0][2][cl] + red[0][3][cl];
    s1 = red[1][0][cl] + red[1][1][cl] + red[1][2][cl] + red[1][3][cl];
    float mu = s0 * invN;
    float var = s1 * invN - mu * mu;   // biased var (ddof=0)
    float is = rsqrtf(var + 1e-5f);
    float scv = gamma[c] * is;
    scale[c] = scv;
    shift[c] = beta[c] - mu * scv;
  }
}

// ---------------- launch ----------------
extern "C" void kernel_launch(void* const* d_in, const int* in_sizes, int n_in,
                              void* d_out, int out_size, void* d_ws, size_t ws_size,
                              hipStream_t stream) {
  const float* x   = (const float*)d_in[0];
  const int*   ei  = (const int*)d_in[1];
  const float* W1  = (const float*)d_in[2];
  // d_in[3] = b1: absorbed by BN (mean subtraction cancels it)
  const float* g1  = (const float*)d_in[4];
  const float* be1 = (const float*)d_in[5];
  const float* W2  = (const float*)d_in[6];
  // d_in[7] = b2: absorbed by BN
  const float* g2  = (const float*)d_in[8];
  const float* be2 = (const float*)d_in[9];
  const float* Wl  = (const float*)d_in[10];
  const float* bl  = (const float*)d_in[11];
  float* out = (float*)d_out;

  const int N  = in_sizes[0] / 128;          // 50000
  const int E  = in_sizes[1] / 2;            // 500000
  const int Mp = ((N + 127) / 128) * 128;    // 50048 = 391*128 = 782*64
  const int GX = Mp / 128;                   // 391 m-tiles (non-final)
  const int GB = (GX + 7) / 8;               // 49 xcd-groups

  char* p = (char*)d_ws;
  auto carve = [&](size_t bytes) { void* r = (void*)p; p += (bytes + 255) & ~(size_t)255; return r; };
  int*   deg   = (int*)carve(sizeof(int) * N);
  int*   cur   = (int*)carve(sizeof(int) * N);
  int*   roff  = (int*)carve(sizeof(int) * (N + 1));
  int2*  csr   = (int2*)carve(sizeof(int2) * E);   // {src, dinv[src]}
  float* dinv  = (float*)carve(sizeof(float) * N);
  float* part1 = (float*)carve(sizeof(float) * 2 * (size_t)GX * 256);
  float* part2 = (float*)carve(sizeof(float) * 2 * (size_t)GX * 512);
  float* sc1   = (float*)carve(sizeof(float) * 256);
  float* sh1   = (float*)carve(sizeof(float) * 256);
  float* sc2   = (float*)carve(sizeof(float) * 512);
  float* sh2   = (float*)carve(sizeof(float) * 512);
  bf16*  w1t   = (bf16*)carve(sizeof(bf16) * 256 * 128);
  bf16*  w2t   = (bf16*)carve(sizeof(bf16) * 512 * 256);
  bf16*  wlt   = (bf16*)carve(sizeof(bf16) * 128 * 512);
  bf16*  xb    = (bf16*)carve(sizeof(bf16) * (size_t)Mp * 128);
  bf16*  ax1   = (bf16*)carve(sizeof(bf16) * (size_t)Mp * 128);  // agg(x)
  bf16*  t1    = (bf16*)carve(sizeof(bf16) * (size_t)Mp * 256);  // ax1 @ W1
  bf16*  ax2   = (bf16*)carve(sizeof(bf16) * (size_t)Mp * 256);  // agg(relu(bn(t1)))
  bf16*  t2    = (bf16*)carve(sizeof(bf16) * (size_t)Mp * 512);  // ax2 @ W2 (raw; BN fused into final GEMM)
  (void)n_in; (void)out_size; (void)ws_size;

  const int gE = (E + 255) / 256;
  const int nx = (int)(((size_t)N * 128 / 4 + 255) / 256);
  // cvt first (also inits deg/cur: nx=6250 blocks cover N via first 196)
  k_cvt<<<nx + 896, 256, 0, stream>>>(x, xb, (size_t)N * 128, nx, W1, W2, Wl,
                                      w1t, w2t, wlt, deg, cur, N);
  k_count<<<gE, 256, 0, stream>>>(ei, deg, E);
  k_scan<<<1, 1024, 0, stream>>>(deg, roff, dinv, N);
  k_scatter<<<gE, 256, 0, stream>>>(ei, roff, cur, csr, dinv, E);

  // layer 1: aggregate first (S commutes with dense transform), then GEMM(+stats)
  k_agg<128, false><<<N, 64, 0, stream>>>(xb, ax1, csr, roff, dinv, nullptr, nullptr, N);
  k_gemm<128, 256, false><<<dim3(8, 2 * GB), 256, 0, stream>>>(ax1, w1t, t1, nullptr, nullptr, part1, nullptr, nullptr, N);
  k_bnfinal<<<4, 256, 0, stream>>>(part1, g1, be1, sc1, sh1, 256, GX, 1.f / (float)N);

  // layer 2: gather applies BN1+ReLU on the fly
  k_agg<256, true><<<N, 64, 0, stream>>>(t1, ax2, csr, roff, dinv, sc1, sh1, N);
  k_gemm<256, 512, false><<<dim3(8, 4 * GB), 256, 0, stream>>>(ax2, w2t, t2, nullptr, nullptr, part2, nullptr, nullptr, N);
  k_bnfinal<<<8, 256, 0, stream>>>(part2, g2, be2, sc2, sh2, 512, GX, 1.f / (float)N);

  // final linear: out = relu(bn2(t2)) @ Wl + bl — BN2+ReLU fused into A-staging
  k_gemm<512, 128, true><<<dim3(1, Mp / 64), 256, 0, stream>>>(t2, wlt, nullptr, out, bl, nullptr, sc2, sh2, N);
}

// Round 12
// 338.104 us; speedup vs baseline: 1.2905x; 1.2905x over previous
//
#include <hip/hip_runtime.h>
#include <cstdint>
#include <cstddef>

typedef __bf16 bf16;
typedef bf16 bf16x2 __attribute__((ext_vector_type(2)));
typedef bf16 bf16x4 __attribute__((ext_vector_type(4)));
typedef bf16 bf16x8 __attribute__((ext_vector_type(8)));
typedef float f32x4 __attribute__((ext_vector_type(4)));

// async global->LDS, 16B per lane; dest must be wave-uniform base (HW adds lane*16)
__device__ __forceinline__ void gll16(const void* g, void* l) {
  __builtin_amdgcn_global_load_lds((__attribute__((address_space(1))) void*)g,
                                   (__attribute__((address_space(3))) void*)l, 16, 0, 0);
}

// ---------------- graph preprocessing ----------------
__global__ void k_count(const int* __restrict__ ei, int* __restrict__ deg, int E) {
  int e = blockIdx.x * 256 + threadIdx.x;
  if (e < E) atomicAdd(&deg[ei[E + e]], 1);   // dst = ei[E+e]
}

// R21: scan reverted to the proven 3-kernel hierarchical form. The R20
// single-workgroup fusion measured 107.7us (one CU, ~49 serial cross-XCD
// L2-miss loads per thread, occupancy 0.14% -> zero latency hiding).
__global__ __launch_bounds__(256) void k_scan1(const int* __restrict__ deg,
                                               int* __restrict__ bsum, int N) {
  int t = threadIdx.x;
  int i = blockIdx.x * 256 + t;
  int v = (i < N) ? deg[i] - 1 : 0;
#pragma unroll
  for (int off = 32; off > 0; off >>= 1) v += __shfl_down(v, off, 64);
  __shared__ int red[4];
  if ((t & 63) == 0) red[t >> 6] = v;
  __syncthreads();
  if (t == 0) bsum[blockIdx.x] = red[0] + red[1] + red[2] + red[3];
}

__global__ __launch_bounds__(256) void k_scan2(const int* __restrict__ bsum,
                                               int* __restrict__ bpre, int B) {
  __shared__ int s[256];
  int t = threadIdx.x;
  int v = (t < B) ? bsum[t] : 0;
  s[t] = v;
  __syncthreads();
  for (int off = 1; off < 256; off <<= 1) {
    int add = (t >= off) ? s[t - off] : 0;
    __syncthreads();
    s[t] += add;
    __syncthreads();
  }
  if (t < B) bpre[t] = s[t] - v;   // exclusive
}

__global__ __launch_bounds__(256) void k_scan3(const int* __restrict__ deg,
                                               const int* __restrict__ bpre,
                                               int* __restrict__ roff,
                                               float* __restrict__ dinv, int N) {
  __shared__ int s[256];
  int t = threadIdx.x;
  int i = blockIdx.x * 256 + t;
  int d = (i < N) ? deg[i] : 1;
  int v = d - 1;
  if (i >= N) v = 0;
  s[t] = v;
  __syncthreads();
  for (int off = 1; off < 256; off <<= 1) {
    int add = (t >= off) ? s[t - off] : 0;
    __syncthreads();
    s[t] += add;
    __syncthreads();
  }
  if (i < N) {
    int base = bpre[blockIdx.x];
    roff[i] = base + s[t] - v;
    dinv[i] = rsqrtf((float)d);
    if (i == N - 1) roff[N] = base + s[t];
  }
}

// csr entry = {src, dinv[src]}: the per-edge weight rides the coalesced index
// load in agg (R16; removed the scattered per-edge dinv gather).
__global__ void k_scatter(const int* __restrict__ ei, const int* __restrict__ roff,
                          int* __restrict__ cur, int2* __restrict__ csr,
                          const float* __restrict__ dinv, int E) {
  int e = blockIdx.x * 256 + threadIdx.x;
  if (e >= E) return;
  int d = ei[E + e];
  int sidx = ei[e];
  int p = atomicAdd(&cur[d], 1);
  int2 val;
  val.x = sidx;
  val.y = __float_as_int(dinv[sidx]);
  csr[roff[d] + p] = val;   // src + weight
}

// ---------------- dtype conversion + deg/cur init (one launch) ----------------
__global__ void k_cvt(const float* __restrict__ x, bf16* __restrict__ xb,
                      size_t totalx, int nx,
                      const float* __restrict__ W1, const float* __restrict__ W2,
                      const float* __restrict__ Wl, bf16* __restrict__ w1t,
                      bf16* __restrict__ w2t, bf16* __restrict__ wlt,
                      int* __restrict__ deg, int* __restrict__ cur, int N) {
  if ((int)blockIdx.x < nx) {
    int ii = blockIdx.x * 256 + threadIdx.x;
    if (ii < N) { deg[ii] = 1; cur[ii] = 0; }   // self-loop degree init, fused
    size_t base = ((size_t)blockIdx.x * 256 + threadIdx.x) * 4;
    if (base >= totalx) return;
    const float4 v = *(const float4*)(x + base);
    bf16x4 o;
    o[0] = (bf16)v.x; o[1] = (bf16)v.y; o[2] = (bf16)v.z; o[3] = (bf16)v.w;
    *(bf16x4*)(xb + base) = o;
  } else {
    int i = (blockIdx.x - nx) * 256 + threadIdx.x;   // covers 229376 exactly
    if (i < 32768) {
      int n = i >> 7, k = i & 127;
      w1t[i] = (bf16)W1[(size_t)k * 256 + n];
    } else if (i < 163840) {
      int j = i - 32768;
      int n = j >> 8, k = j & 255;
      w2t[j] = (bf16)W2[(size_t)k * 512 + n];
    } else {
      int j = i - 163840;
      int n = j >> 9, k = j & 511;
      wlt[j] = (bf16)Wl[(size_t)k * 128 + n];
    }
  }
}

// ---------------- bf16 MFMA GEMM: C[M,NOUT] = A[M,K] @ Bt[NOUT,K]^T ----------------
// Frozen (R12/R15/R17): line-coalesced DMA staging, 2-buffer m97 schedule,
// LDS-transpose epilogue, BN partials; XCD-grouped grid for non-FINAL
// (all NS n-stripes of an m-tile land on the same XCD -> A-panel L2 reuse);
// FINAL fuses BN2+ReLU into reg-staged A.
template<int K, int NOUT, bool FINAL>
__global__ __launch_bounds__(256, 4) void k_gemm(const bf16* __restrict__ A,
                                                 const bf16* __restrict__ Bt,
                                                 bf16* __restrict__ outB,
                                                 float* __restrict__ outF,
                                                 const float* __restrict__ bias,
                                                 float* __restrict__ part,
                                                 const float* __restrict__ scA,
                                                 const float* __restrict__ shA,
                                                 int Mreal) {
  constexpr int MT    = FINAL ? 64 : 128;   // m-tile rows
  constexpr int RPW   = MT / 32;            // 16-row subtiles per wave
  constexpr int NSTEP = K / 32;
  constexpr int SB    = MT * 4 + 512;       // uint4 slots per buffer (A + B)
  constexpr int NAI   = (MT * 4) / 256;     // A DMA issues per thread (2 or 1)
  constexpr int NS    = NOUT / 128;         // n-stripes (1, 2 or 4)
  constexpr int NSH   = (NS == 4) ? 2 : ((NS == 2) ? 1 : 0);

  const int GXr = (Mreal + 127) >> 7;       // real m-tiles (391)
  int mtile, m0, n0;
  if constexpr (!FINAL) {
    mtile = blockIdx.x + ((blockIdx.y >> NSH) << 3);
    if (mtile >= GXr) return;               // uniform exit, before any barrier
    m0 = mtile * 128;
    n0 = (blockIdx.y & (NS - 1)) * 128;
  } else {
    mtile = blockIdx.y;
    m0 = blockIdx.y * MT;
    n0 = 0;
  }

  __shared__ uint4 lds[2 * SB];
  __shared__ float sstm[512];               // stats scratch, DISJOINT from lds
  __shared__ float scsh[FINAL ? 1024 : 4];  // FINAL: scale[512] + shift[512]

  const int tid = threadIdx.x;
  const int wv = tid >> 6;
  const int lane = tid & 63;
  const int q = lane >> 4, mr = lane & 15;
  const int rw = (wv >> 1) * (MT / 2), cw = (wv & 1) * 64;
  const int wslot = wv << 6;
  const int qx = q ^ (mr & 3);   // read-side in-row XOR (row&3 == mr&3)

  // coalesced per-lane global sources: dest granule slot=p*256+tid (linear)
  // holds (row = slot>>2, chunk = (slot&3)^(row&3)) of the current K-step.
  const bf16* srcA[NAI];
#pragma unroll
  for (int p = 0; p < NAI; ++p) {
    int slot = p * 256 + tid;
    int row = slot >> 2;
    int c = (slot & 3) ^ (row & 3);
    srcA[p] = A + (size_t)(m0 + row) * K + c * 8;
  }
  const bf16* srcB[2];
#pragma unroll
  for (int p = 0; p < 2; ++p) {
    int slot = p * 256 + tid;
    int row = slot >> 2;
    int c = (slot & 3) ^ (row & 3);
    srcB[p] = Bt + (size_t)(n0 + row) * K + c * 8;
  }
  const int cA8 = (((tid & 3) ^ ((tid >> 2) & 3))) * 8;   // FINAL A chunk base

  auto issue = [&](int t) {
    uint4* bb = lds + (t & 1) * SB;
    if constexpr (!FINAL) {
#pragma unroll
      for (int p = 0; p < NAI; ++p)
        gll16(srcA[p] + t * 32, bb + p * 256 + wslot);
    }
#pragma unroll
    for (int p = 0; p < 2; ++p)
      gll16(srcB[p] + t * 32, bb + MT * 4 + p * 256 + wslot);
  };

  // FINAL: transform raw A (BN2+ReLU) and write to the linear LDS slot
  auto xformA = [&](bf16x8 ra, int t) {
    int kb = t * 32 + cA8;
    float4 s0 = *(const float4*)&scsh[kb];
    float4 s1 = *(const float4*)&scsh[kb + 4];
    float4 h0 = *(const float4*)&scsh[512 + kb];
    float4 h1 = *(const float4*)&scsh[512 + kb + 4];
    bf16x8 o;
    o[0] = (bf16)fmaxf(0.f, (float)ra[0] * s0.x + h0.x);
    o[1] = (bf16)fmaxf(0.f, (float)ra[1] * s0.y + h0.y);
    o[2] = (bf16)fmaxf(0.f, (float)ra[2] * s0.z + h0.z);
    o[3] = (bf16)fmaxf(0.f, (float)ra[3] * s0.w + h0.w);
    o[4] = (bf16)fmaxf(0.f, (float)ra[4] * s1.x + h1.x);
    o[5] = (bf16)fmaxf(0.f, (float)ra[5] * s1.y + h1.y);
    o[6] = (bf16)fmaxf(0.f, (float)ra[6] * s1.z + h1.z);
    o[7] = (bf16)fmaxf(0.f, (float)ra[7] * s1.w + h1.w);
    lds[(t & 1) * SB + tid] = *(uint4*)&o;
  };

  f32x4 acc[RPW][4];
#pragma unroll
  for (int r = 0; r < RPW; ++r)
#pragma unroll
    for (int c = 0; c < 4; ++c) acc[r][c] = (f32x4){0.f, 0.f, 0.f, 0.f};

  if constexpr (FINAL) {
    for (int i = tid; i < 1024; i += 256) scsh[i] = (i < 512) ? scA[i] : shA[i - 512];
    issue(0);                              // B DMA only
    bf16x8 ra0 = *(const bf16x8*)srcA[0];
    __syncthreads();                       // scsh visible (B also drained)
    xformA(ra0, 0);
    __syncthreads();                       // buf0 A published
  } else {
    issue(0);
    __syncthreads();                       // drains DMA: buf 0 ready
  }

#pragma unroll
  for (int t = 0; t < NSTEP; ++t) {
    bf16x8 raN;
    if (t + 1 < NSTEP) {
      issue(t + 1);                        // in flight across the compute phase
      if constexpr (FINAL) raN = *(const bf16x8*)(srcA[0] + (t + 1) * 32);
    }

    const uint4* bb = lds + (t & 1) * SB;
    const bf16x8* bA = (const bf16x8*)bb;
    const bf16x8* bB = (const bf16x8*)(bb + MT * 4);
    bf16x8 bfr[4];
#pragma unroll
    for (int c = 0; c < 4; ++c) {
      int rb = cw + c * 16 + mr;
      bfr[c] = bB[rb * 4 + qx];
    }
#pragma unroll
    for (int r = 0; r < RPW; ++r) {
      int ra = rw + r * 16 + mr;
      bf16x8 af = bA[ra * 4 + qx];
#pragma unroll
      for (int c = 0; c < 4; ++c)
        acc[r][c] = __builtin_amdgcn_mfma_f32_16x16x32_bf16(af, bfr[c], acc[r][c], 0, 0, 0);
    }
    if constexpr (FINAL) {
      if (t + 1 < NSTEP) xformA(raN, t + 1);   // write buf t+1 A (pre-barrier)
    }
    __syncthreads();   // drains next tile's DMA (after compute) + read fence
  }

  // C/D layout: col = lane&15, row = (lane>>4)*4 + reg (m89/m91-verified)
  if constexpr (!FINAL) {
    bf16* ot = (bf16*)lds;                  // [128][128] bf16, XOR-swizzled cols
#pragma unroll
    for (int c = 0; c < 4; ++c) {
      float s0 = 0.f, s1 = 0.f;
#pragma unroll
      for (int r = 0; r < RPW; ++r) {
#pragma unroll
        for (int i = 0; i < 4; ++i) {
          int rl = rw + r * 16 + q * 4 + i;
          int cl = cw + c * 16 + mr;
          float v = acc[r][c][i];
          ot[rl * 128 + (cl ^ (((rl >> 2) & 3) << 4))] = (bf16)v;
          if (m0 + rl < Mreal) { s0 += v; s1 += v * v; }
        }
      }
      s0 += __shfl_xor(s0, 16, 64); s0 += __shfl_xor(s0, 32, 64);
      s1 += __shfl_xor(s1, 16, 64); s1 += __shfl_xor(s1, 32, 64);
      if (q == 0) {
        sstm[wv * 64 + c * 16 + mr] = s0;
        sstm[256 + wv * 64 + c * 16 + mr] = s1;
      }
    }
    __syncthreads();
    {
      // combine wave pairs, plain-store per-block partials (no atomics)
      int ssel = tid >> 7, cl = tid & 127;
      int hi = cl >> 6, lo = cl & 63;
      float v = sstm[ssel * 256 + hi * 64 + lo] + sstm[ssel * 256 + (hi + 2) * 64 + lo];
      part[((size_t)ssel * GXr + mtile) * NOUT + n0 + cl] = v;
    }
    // full-line coalesced stores: 16 lanes cover one 256B row
#pragma unroll
    for (int p = 0; p < 8; ++p) {
      int rl = p * 16 + (tid >> 4), c8 = tid & 15;
      uint4 v = *(const uint4*)(ot + rl * 128 + ((c8 * 8) ^ (((rl >> 2) & 3) << 4)));
      *(uint4*)(outB + (size_t)(m0 + rl) * NOUT + n0 + c8 * 8) = v;
    }
  } else {
    // FINAL LDS is 2*SB*16 = 24576 B; stage the [64][128] f32 tile in two halves.
    float* otf = (float*)lds;
#pragma unroll
    for (int h = 0; h < 2; ++h) {
      __syncthreads();
#pragma unroll
      for (int c = 0; c < 4; ++c)
#pragma unroll
        for (int r = 0; r < RPW; ++r)
#pragma unroll
          for (int i = 0; i < 4; ++i) {
            int rl = rw + r * 16 + q * 4 + i;
            if ((rl >> 5) != h) continue;   // rows [h*32, h*32+32)
            int cl = cw + c * 16 + mr;
            otf[(rl - h * 32) * 128 + (cl ^ (((rl >> 2) & 3) << 4))] = acc[r][c][i];
          }
      __syncthreads();
#pragma unroll
      for (int p = 0; p < 4; ++p) {
        int rl = p * 8 + (tid >> 5), c4 = tid & 31;
        int rg = m0 + h * 32 + rl;
        if (rg < Mreal) {
          float4 v = *(const float4*)(otf + rl * 128 + ((c4 * 4) ^ ((((rl + h * 32) >> 2) & 3) << 4)));
          const float4 bv = *(const float4*)(bias + c4 * 4);
          v.x += bv.x; v.y += bv.y; v.z += bv.z; v.w += bv.w;
          *(float4*)(outF + (size_t)rg * 128 + c4 * 4) = v;
        }
      }
    }
  }
}

// ---------------- CSR aggregation (one wave per node) ----------------
// R17 form (best measured: 40.7us). At the random-gather fabric floor:
// ~120-127MB of L2-miss traffic at ~3TB/s scattered-request bandwidth.
// Failed alternatives: R13 half-wave pairing (+5.4us), R14 pad-to-8 (+3.6us),
// R18 channel-split (+1.6us, FETCH barely moved - slices run concurrently
// and reuse is scattered across 8 incoherent L2s regardless).
template<int C, bool BN>
__global__ __launch_bounds__(64) void k_agg(const bf16* __restrict__ h,
                                            bf16* __restrict__ g,
                                            const int2* __restrict__ csr,
                                            const int* __restrict__ roff,
                                            const float* __restrict__ dinv,
                                            const float* __restrict__ scale,
                                            const float* __restrict__ shift,
                                            int N) {
  constexpr int VPL = C / 64;   // channels per lane: 2 or 4
  const int lane = threadIdx.x;
  const int v = blockIdx.x;
  if (v >= N) return;
  float sc[VPL], sh[VPL];
  if constexpr (BN) {
#pragma unroll
    for (int u = 0; u < VPL; ++u) { sc[u] = scale[lane * VPL + u]; sh[u] = shift[lane * VPL + u]; }
  }
  const float dv = dinv[v];
  float acc[VPL];
#pragma unroll
  for (int u = 0; u < VPL; ++u) acc[u] = 0.f;

  auto loadrow = [&](int src, float* o) {
    const bf16* hr = h + (size_t)src * C + lane * VPL;
    if constexpr (VPL == 2) {
      bf16x2 t = *(const bf16x2*)hr;
      o[0] = (float)t[0]; o[1] = (float)t[1];
    } else {
      bf16x4 t = *(const bf16x4*)hr;
#pragma unroll
      for (int u = 0; u < 4; ++u) o[u] = (float)t[u];
    }
  };
  auto addrow = [&](const float* vv, float ww) {
#pragma unroll
    for (int u = 0; u < VPL; ++u) {
      float xx = vv[u];
      if constexpr (BN) xx = fmaxf(0.f, xx * sc[u] + sh[u]);
      acc[u] += ww * xx;
    }
  };

  {   // self loop (becomes dv^2 after final *dv)
    float vv[VPL];
    loadrow(v, vv);
    addrow(vv, dv);
  }
  const int beg = roff[v], end = roff[v + 1];
  for (int base = beg; base < end; base += 64) {
    int cnt = min(64, end - base);
    int s = 0; float w = 0.f;
    if (lane < cnt) {
      int2 pr = csr[base + lane];
      s = pr.x; w = __int_as_float(pr.y);
    }
    int j = 0;
    for (; j + 8 <= cnt; j += 8) {
      int ss[8]; float ww[8];
#pragma unroll
      for (int k = 0; k < 8; ++k) {
        ss[k] = __shfl(s, j + k, 64);
        ww[k] = __shfl(w, j + k, 64);
      }
      float vals[8][VPL];
#pragma unroll
      for (int k = 0; k < 8; ++k) loadrow(ss[k], vals[k]);
#pragma unroll
      for (int k = 0; k < 8; ++k) addrow(vals[k], ww[k]);
    }
    for (; j + 4 <= cnt; j += 4) {
      int sa = __shfl(s, j, 64),     sb = __shfl(s, j + 1, 64);
      int sc2 = __shfl(s, j + 2, 64), sd = __shfl(s, j + 3, 64);
      float wa = __shfl(w, j, 64),     wb = __shfl(w, j + 1, 64);
      float wc = __shfl(w, j + 2, 64), wd = __shfl(w, j + 3, 64);
      float va[VPL], vb[VPL], vc[VPL], vd[VPL];
      loadrow(sa, va); loadrow(sb, vb); loadrow(sc2, vc); loadrow(sd, vd);
      addrow(va, wa); addrow(vb, wb); addrow(vc, wc); addrow(vd, wd);
    }
    for (; j < cnt; ++j) {
      int sj = __shfl(s, j, 64);
      float wj = __shfl(w, j, 64);
      float vv[VPL];
      loadrow(sj, vv);
      addrow(vv, wj);
    }
  }

  bf16* gv = g + (size_t)v * C + lane * VPL;
  if constexpr (VPL == 2) {
    bf16x2 o;
    o[0] = (bf16)(acc[0] * dv); o[1] = (bf16)(acc[1] * dv);
    *(bf16x2*)gv = o;
  } else {
    bf16x4 o;
#pragma unroll
    for (int u = 0; u < 4; ++u) o[u] = (bf16)(acc[u] * dv);
    *(bf16x4*)gv = o;
  }
}

// ---------------- BatchNorm: reduce per-block partials + finalize ----------------
// part layout: [2][GX][C]; loads coalesced (64 lanes = 64 consecutive cols)
__global__ __launch_bounds__(256) void k_bnfinal(const float* __restrict__ part,
                                                 const float* __restrict__ gamma,
                                                 const float* __restrict__ beta,
                                                 float* __restrict__ scale,
                                                 float* __restrict__ shift,
                                                 int C, int GX, float invN) {
  __shared__ float red[2][4][64];
  int t = threadIdx.x;
  int cl = t & 63, seg = t >> 6;
  int c = blockIdx.x * 64 + cl;
  float s0 = 0.f, s1 = 0.f;
  for (int b = seg; b < GX; b += 4) {
    s0 += part[(size_t)b * C + c];
    s1 += part[(size_t)(GX + b) * C + c];
  }
  red[0][seg][cl] = s0; red[1][seg][cl] = s1;
  __syncthreads();
  if (seg == 0) {
    s0 = red[0][0][cl] + red[0][1][cl] + red[0][2][cl] + red[0][3][cl];
    s1 = red[1][0][cl] + red[1][1][cl] + red[1][2][cl] + red[1][3][cl];
    float mu = s0 * invN;
    float var = s1 * invN - mu * mu;   // biased var (ddof=0)
    float is = rsqrtf(var + 1e-5f);
    float scv = gamma[c] * is;
    scale[c] = scv;
    shift[c] = beta[c] - mu * scv;
  }
}

// ---------------- launch ----------------
extern "C" void kernel_launch(void* const* d_in, const int* in_sizes, int n_in,
                              void* d_out, int out_size, void* d_ws, size_t ws_size,
                              hipStream_t stream) {
  const float* x   = (const float*)d_in[0];
  const int*   ei  = (const int*)d_in[1];
  const float* W1  = (const float*)d_in[2];
  // d_in[3] = b1: absorbed by BN (mean subtraction cancels it)
  const float* g1  = (const float*)d_in[4];
  const float* be1 = (const float*)d_in[5];
  const float* W2  = (const float*)d_in[6];
  // d_in[7] = b2: absorbed by BN
  const float* g2  = (const float*)d_in[8];
  const float* be2 = (const float*)d_in[9];
  const float* Wl  = (const float*)d_in[10];
  const float* bl  = (const float*)d_in[11];
  float* out = (float*)d_out;

  const int N  = in_sizes[0] / 128;          // 50000
  const int E  = in_sizes[1] / 2;            // 500000
  const int Mp = ((N + 127) / 128) * 128;    // 50048 = 391*128 = 782*64
  const int NB = (N + 255) / 256;            // scan blocks (196)
  const int GX = Mp / 128;                   // 391 m-tiles (non-final)
  const int GB = (GX + 7) / 8;               // 49 xcd-groups

  char* p = (char*)d_ws;
  auto carve = [&](size_t bytes) { void* r = (void*)p; p += (bytes + 255) & ~(size_t)255; return r; };
  int*   deg   = (int*)carve(sizeof(int) * N);
  int*   cur   = (int*)carve(sizeof(int) * N);
  int*   roff  = (int*)carve(sizeof(int) * (N + 1));
  int2*  csr   = (int2*)carve(sizeof(int2) * E);   // {src, dinv[src]}
  int*   bsum  = (int*)carve(sizeof(int) * 256);
  int*   bpre  = (int*)carve(sizeof(int) * 256);
  float* dinv  = (float*)carve(sizeof(float) * N);
  float* part1 = (float*)carve(sizeof(float) * 2 * (size_t)GX * 256);
  float* part2 = (float*)carve(sizeof(float) * 2 * (size_t)GX * 512);
  float* sc1   = (float*)carve(sizeof(float) * 256);
  float* sh1   = (float*)carve(sizeof(float) * 256);
  float* sc2   = (float*)carve(sizeof(float) * 512);
  float* sh2   = (float*)carve(sizeof(float) * 512);
  bf16*  w1t   = (bf16*)carve(sizeof(bf16) * 256 * 128);
  bf16*  w2t   = (bf16*)carve(sizeof(bf16) * 512 * 256);
  bf16*  wlt   = (bf16*)carve(sizeof(bf16) * 128 * 512);
  bf16*  xb    = (bf16*)carve(sizeof(bf16) * (size_t)Mp * 128);
  bf16*  ax1   = (bf16*)carve(sizeof(bf16) * (size_t)Mp * 128);  // agg(x)
  bf16*  t1    = (bf16*)carve(sizeof(bf16) * (size_t)Mp * 256);  // ax1 @ W1
  bf16*  ax2   = (bf16*)carve(sizeof(bf16) * (size_t)Mp * 256);  // agg(relu(bn(t1)))
  bf16*  t2    = (bf16*)carve(sizeof(bf16) * (size_t)Mp * 512);  // ax2 @ W2 (raw; BN fused into final GEMM)
  (void)n_in; (void)out_size; (void)ws_size;

  const int gE = (E + 255) / 256;
  const int nx = (int)(((size_t)N * 128 / 4 + 255) / 256);
  // cvt first (also inits deg/cur: nx=6250 blocks cover N via first 196)
  k_cvt<<<nx + 896, 256, 0, stream>>>(x, xb, (size_t)N * 128, nx, W1, W2, Wl,
                                      w1t, w2t, wlt, deg, cur, N);
  k_count<<<gE, 256, 0, stream>>>(ei, deg, E);
  k_scan1<<<NB, 256, 0, stream>>>(deg, bsum, N);
  k_scan2<<<1, 256, 0, stream>>>(bsum, bpre, NB);
  k_scan3<<<NB, 256, 0, stream>>>(deg, bpre, roff, dinv, N);
  k_scatter<<<gE, 256, 0, stream>>>(ei, roff, cur, csr, dinv, E);

  // layer 1: aggregate first (S commutes with dense transform), then GEMM(+stats)
  k_agg<128, false><<<N, 64, 0, stream>>>(xb, ax1, csr, roff, dinv, nullptr, nullptr, N);
  k_gemm<128, 256, false><<<dim3(8, 2 * GB), 256, 0, stream>>>(ax1, w1t, t1, nullptr, nullptr, part1, nullptr, nullptr, N);
  k_bnfinal<<<4, 256, 0, stream>>>(part1, g1, be1, sc1, sh1, 256, GX, 1.f / (float)N);

  // layer 2: gather applies BN1+ReLU on the fly
  k_agg<256, true><<<N, 64, 0, stream>>>(t1, ax2, csr, roff, dinv, sc1, sh1, N);
  k_gemm<256, 512, false><<<dim3(8, 4 * GB), 256, 0, stream>>>(ax2, w2t, t2, nullptr, nullptr, part2, nullptr, nullptr, N);
  k_bnfinal<<<8, 256, 0, stream>>>(part2, g2, be2, sc2, sh2, 512, GX, 1.f / (float)N);

  // final linear: out = relu(bn2(t2)) @ Wl + bl — BN2+ReLU fused into A-staging
  k_gemm<512, 128, true><<<dim3(1, Mp / 64), 256, 0, stream>>>(t2, wlt, nullptr, out, bl, nullptr, sc2, sh2, N);
}